// Round 11
// baseline (288.227 us; speedup 1.0000x reference)
//
#include <hip/hip_runtime.h>
#include <hip/hip_fp16.h>

#define DH 256   // feature dim (D == H == 256)

typedef _Float16 half8 __attribute__((ext_vector_type(8)));
typedef float floatx4 __attribute__((ext_vector_type(4)));

// ---------------------------------------------------------------- setup kernels

// merged: init deg/fill (blocks [0,nb)) + W transpose/cast (blocks [nb, nb+128))
__global__ __launch_bounds__(256) void k_init_tw(float* __restrict__ deg,
                                                 int* __restrict__ fill, int n,
                                                 const float* __restrict__ W1,
                                                 _Float16* __restrict__ Wt1,
                                                 const float* __restrict__ W2,
                                                 _Float16* __restrict__ Wt2) {
    __shared__ float t[32][33];
    int nb = (n + 255) / 256;
    int b = blockIdx.x;
    if (b < nb) {
        int i = b * 256 + threadIdx.x;
        if (i < n) { deg[i] = 1.0f; fill[i] = 0; }
        return;
    }
    b -= nb;                       // 0..127 : [z(1)][y(3)][x(3)]
    const float* W = (b & 64) ? W2 : W1;
    _Float16* Wt = (b & 64) ? Wt2 : Wt1;
    int bx = (b & 7) * 32, by = ((b >> 3) & 7) * 32;
    int tx = threadIdx.x & 31, ty = threadIdx.x >> 5;
#pragma unroll
    for (int r = 0; r < 32; r += 8)
        t[ty + r][tx] = W[(size_t)(by + ty + r) * DH + bx + tx];
    __syncthreads();
#pragma unroll
    for (int r = 0; r < 32; r += 8)
        Wt[(size_t)(bx + ty + r) * DH + by + tx] = (_Float16)t[tx][ty + r];
}

__global__ void k_deg(const int* __restrict__ dst, float* __restrict__ deg, int e) {
    int i = blockIdx.x * blockDim.x + threadIdx.x;
    if (i < e) atomicAdd(&deg[dst[i]], 1.0f);
}

// ---- hierarchical exclusive scan of (int)deg -> row_ptr[0..n]; also dinv ----
__global__ __launch_bounds__(1024) void k_scan1(const float* __restrict__ deg,
                                                float* __restrict__ dinv,
                                                int* __restrict__ row_ptr,
                                                int* __restrict__ part, int n) {
    __shared__ int sd[1024];
    int tid = threadIdx.x;
    int i = blockIdx.x * 1024 + tid;
    float dv = (i < n) ? deg[i] : 1.f;
    if (i < n) dinv[i] = rsqrtf(dv);
    int v = (i < n) ? (int)dv : 0;
    sd[tid] = v;
    __syncthreads();
    for (int off = 1; off < 1024; off <<= 1) {
        int t = (tid >= off) ? sd[tid - off] : 0;
        __syncthreads();
        sd[tid] += t;
        __syncthreads();
    }
    if (i < n) row_ptr[i] = sd[tid] - v;
    if (tid == 1023) part[blockIdx.x] = sd[1023];
}

// single-wave shuffle scan of block totals
__global__ void k_scan2(int* __restrict__ part, int* __restrict__ row_ptr,
                        int nparts, int n) {
    int lane = threadIdx.x & 63;
    int carry = 0;
    for (int base = 0; base < nparts; base += 64) {
        int i = base + lane;
        int v = (i < nparts) ? part[i] : 0;
        int orig = v;
        for (int off = 1; off < 64; off <<= 1) {
            int t = __shfl_up(v, off);
            if (lane >= off) v += t;
        }
        if (i < nparts) part[i] = carry + v - orig;   // exclusive
        int tot = __shfl(v, 63);
        carry += tot;
    }
    if (lane == 0) row_ptr[n] = carry;
}

// phase 3: add block offsets; also write self-loop CSR entry
__global__ __launch_bounds__(1024) void k_scan3(int* __restrict__ row_ptr,
                                                const int* __restrict__ part,
                                                const float* __restrict__ dinv,
                                                int* __restrict__ col,
                                                float* __restrict__ wgt,
                                                int* __restrict__ fill, int n) {
    int i = blockIdx.x * 1024 + threadIdx.x;
    if (i < n) {
        int rp = row_ptr[i] + part[blockIdx.x];
        row_ptr[i] = rp;
        col[rp] = i;
        float d = dinv[i];
        wgt[rp] = d * d;
        fill[i] = 1;
    }
}

__global__ void k_csr(const int* __restrict__ src, const int* __restrict__ dst,
                      const float* __restrict__ dinv, const int* __restrict__ row_ptr,
                      int* __restrict__ fill, int* __restrict__ col,
                      float* __restrict__ wgt, int e) {
    int i = blockIdx.x * blockDim.x + threadIdx.x;
    if (i < e) {
        int s0 = src[i], d0 = dst[i];
        int p = row_ptr[d0] + atomicAdd(&fill[d0], 1);
        col[p] = s0;
        wgt[p] = dinv[s0] * dinv[d0];
    }
}

// ---------------------------------------------------------------- MFMA GEMM
// C[m][0:256] (f16) = X[m][0:256] @ W.  W in registers (wfrag[2][8]/wave).
// ONE 64-row tile per block, single 32KB LDS buffer, one barrier — block-level
// parallelism (782 blocks, ~2-3/CU) hides the stage latency (m114 overlap).
// XOR-swizzled 16B granules: phys_g = g ^ (row&7) -> 2-way (free) on both
// ds_write and ds_read. AF32: converts f32->f16 during staging (fused cast).

template <bool AF32>
__global__ __launch_bounds__(512, 4) void k_gemm_lds(const void* __restrict__ Av,
                                                     const _Float16* __restrict__ Wt,
                                                     _Float16* __restrict__ C,
                                                     int n) {
    __shared__ _Float16 lds[64 * 256];   // 32KB
    int tid = threadIdx.x;
    int wave = tid >> 6, lane = tid & 63;
    int lm = lane & 15;        // row within 16-row fragment (D col)
    int kg = lane >> 4;        // k-group 0..3
    int c0 = wave * 32;        // wave's output-column base
    int sr = tid >> 3;         // staging row 0..63
    int sp = tid & 7;          // staging part (32 f16 = 4 granules)

    const float*    Af = (const float*)Av;
    const _Float16* Ah = (const _Float16*)Av;

    half8 wfrag[2][8];
#pragma unroll
    for (int jj = 0; jj < 2; jj++)
#pragma unroll
        for (int s = 0; s < 8; s++)
            wfrag[jj][s] = *(const half8*)(Wt + (size_t)(c0 + jj * 16 + lm) * DH + s * 32 + kg * 8);

    int t = blockIdx.x;
    int sxor = sr & 7;
    int rxor = lm & 7;

    // stage this block's tile
    {
        int m = min(t * 64 + sr, n - 1);
        _Float16* d = lds + sr * 256;
        if (AF32) {
            const float* g = Af + (size_t)m * DH + sp * 32;
#pragma unroll
            for (int j = 0; j < 4; j++) {
                float4 a = *(const float4*)(g + j * 8);
                float4 b = *(const float4*)(g + j * 8 + 4);
                half8 st;
                st[0] = (_Float16)a.x; st[1] = (_Float16)a.y;
                st[2] = (_Float16)a.z; st[3] = (_Float16)a.w;
                st[4] = (_Float16)b.x; st[5] = (_Float16)b.y;
                st[6] = (_Float16)b.z; st[7] = (_Float16)b.w;
                *(half8*)(d + (((sp * 4 + j) ^ sxor) * 8)) = st;
            }
        } else {
            const _Float16* g = Ah + (size_t)m * DH + sp * 32;
            half8 st[4];
#pragma unroll
            for (int j = 0; j < 4; j++) st[j] = *(const half8*)(g + j * 8);
#pragma unroll
            for (int j = 0; j < 4; j++)
                *(half8*)(d + (((sp * 4 + j) ^ sxor) * 8)) = st[j];
        }
    }
    __syncthreads();

#pragma unroll
    for (int rf = 0; rf < 4; rf++) {
        floatx4 a0 = {0.f, 0.f, 0.f, 0.f};
        floatx4 a1 = {0.f, 0.f, 0.f, 0.f};
        const _Float16* lrow = lds + (rf * 16 + lm) * 256;
#pragma unroll
        for (int s = 0; s < 8; s++) {
            half8 b = *(const half8*)(lrow + (((s * 4 + kg) ^ rxor) * 8));
            a0 = __builtin_amdgcn_mfma_f32_16x16x32_f16(wfrag[0][s], b, a0, 0, 0, 0);
            a1 = __builtin_amdgcn_mfma_f32_16x16x32_f16(wfrag[1][s], b, a1, 0, 0, 0);
        }
        int m = t * 64 + rf * 16 + lm;
        if (m < n) {
            _Float16* crow = C + (size_t)m * DH + c0 + kg * 4;
            __half2 h0 = __float22half2_rn(make_float2(a0[0], a0[1]));
            __half2 h1 = __float22half2_rn(make_float2(a0[2], a0[3]));
            uint2 u;
            u.x = *(unsigned int*)&h0; u.y = *(unsigned int*)&h1;
            *(uint2*)crow = u;
            h0 = __float22half2_rn(make_float2(a1[0], a1[1]));
            h1 = __float22half2_rn(make_float2(a1[2], a1[3]));
            u.x = *(unsigned int*)&h0; u.y = *(unsigned int*)&h1;
            *(uint2*)(crow + 16) = u;
        }
    }
}

// ---------------------------------------------------------------- aggregation
// one WAVE per dst node. Lane q holds col/wgt of edge p0+q (one vector load
// per 64 edges); cols broadcast via shfl; 8 gathers in flight. Fabric-bound
// at ~4 TB/s (8-XCD L2 replication floor) — structure frozen since R10.

__device__ __forceinline__ float4 agg_core(const __half* __restrict__ A,
                                           const int* __restrict__ row_ptr,
                                           const int* __restrict__ col,
                                           const float* __restrict__ wgt,
                                           int node, int lane) {
    int p0 = row_ptr[node], p1 = row_ptr[node + 1];
    const __half* Al = A + lane * 4;
    float a0 = 0.f, a1 = 0.f, a2 = 0.f, a3 = 0.f;
    for (int base = p0; base < p1; base += 64) {
        int idx = base + lane;
        int   cl = col[min(idx, p1 - 1)];
        float wl = (idx < p1) ? wgt[idx] : 0.f;
        int cnt = min(p1 - base, 64);
        for (int q0 = 0; q0 < cnt; q0 += 8) {
            uint2 u[8];
            float w[8];
#pragma unroll
            for (int q = 0; q < 8; q++) {
                int c = __shfl(cl, q0 + q);
                w[q] = __shfl(wl, q0 + q);
                u[q] = *(const uint2*)(Al + (size_t)c * DH);
            }
#pragma unroll
            for (int q = 0; q < 8; q++) {
                float2 fa = __half22float2(*(__half2*)&u[q].x);
                float2 fb = __half22float2(*(__half2*)&u[q].y);
                a0 += w[q] * fa.x;
                a1 += w[q] * fa.y;
                a2 += w[q] * fb.x;
                a3 += w[q] * fb.y;
            }
        }
    }
    return make_float4(a0, a1, a2, a3);
}

// variant 1: f16 output (h1, feeds gemm2)
__global__ __launch_bounds__(256) void k_agg_h(const __half* __restrict__ A,
                                               const int* __restrict__ row_ptr,
                                               const int* __restrict__ col,
                                               const float* __restrict__ wgt,
                                               const float* __restrict__ bias,
                                               __half* __restrict__ out, int n) {
    int node = (blockIdx.x << 2) + (threadIdx.x >> 6);
    int lane = threadIdx.x & 63;
    if (node >= n) return;
    node = __builtin_amdgcn_readfirstlane(node);
    float4 a = agg_core(A, row_ptr, col, wgt, node, lane);
    int f = lane * 4;
    float4 b4 = *(const float4*)&bias[f];
    __half2 h0 = __float22half2_rn(make_float2(fmaxf(a.x + b4.x, 0.f), fmaxf(a.y + b4.y, 0.f)));
    __half2 h1 = __float22half2_rn(make_float2(fmaxf(a.z + b4.z, 0.f), fmaxf(a.w + b4.w, 0.f)));
    uint2 u;
    u.x = *(unsigned int*)&h0;
    u.y = *(unsigned int*)&h1;
    *(uint2*)(out + (size_t)node * DH + f) = u;
}

// variant 2: f32 output (final h) + fused edge-predictor dot s[node]=h.We
__global__ __launch_bounds__(256) void k_agg_f(const __half* __restrict__ A,
                                               const int* __restrict__ row_ptr,
                                               const int* __restrict__ col,
                                               const float* __restrict__ wgt,
                                               const float* __restrict__ bias,
                                               const float* __restrict__ We,
                                               float* __restrict__ out,
                                               float* __restrict__ s, int n) {
    int node = (blockIdx.x << 2) + (threadIdx.x >> 6);
    int lane = threadIdx.x & 63;
    if (node >= n) return;
    node = __builtin_amdgcn_readfirstlane(node);
    float4 a = agg_core(A, row_ptr, col, wgt, node, lane);
    int f = lane * 4;
    float4 b4 = *(const float4*)&bias[f];
    float4 v = make_float4(fmaxf(a.x + b4.x, 0.f), fmaxf(a.y + b4.y, 0.f),
                           fmaxf(a.z + b4.z, 0.f), fmaxf(a.w + b4.w, 0.f));
    *(float4*)&out[(size_t)node * DH + f] = v;

    float4 wv = *(const float4*)&We[f];
    float d = v.x * wv.x + v.y * wv.y + v.z * wv.z + v.w * wv.w;
#pragma unroll
    for (int off = 32; off > 0; off >>= 1) d += __shfl_down(d, off);
    if (lane == 0) s[node] = d;
}

// ---------------------------------------------------------------- edge output

__global__ void k_y(const int* __restrict__ src, const int* __restrict__ dst,
                    const float* __restrict__ s, const float* __restrict__ be,
                    float* __restrict__ y, int e) {
    int i = blockIdx.x * blockDim.x + threadIdx.x;
    if (i < e) y[i] = 0.5f * (s[src[i]] + s[dst[i]]) + be[0];
}

// ---------------------------------------------------------------- launch

extern "C" void kernel_launch(void* const* d_in, const int* in_sizes, int n_in,
                              void* d_out, int out_size, void* d_ws, size_t ws_size,
                              hipStream_t stream) {
    const float* x  = (const float*)d_in[0];
    const int*   ei = (const int*)d_in[1];
    const float* W1 = (const float*)d_in[2];
    const float* b1 = (const float*)d_in[3];
    const float* W2 = (const float*)d_in[4];
    const float* b2 = (const float*)d_in[5];
    const float* We = (const float*)d_in[6];
    const float* be = (const float*)d_in[7];

    int n = in_sizes[0] / DH;
    int e = in_sizes[1] / 2;
    const int* src = ei;
    const int* dst = ei + e;

    float* out_h = (float*)d_out;                   // n*DH f32 (final)
    float* out_y = out_h + (size_t)n * DH;          // e

    char* w = (char*)d_ws;
    _Float16* A   = (_Float16*)w;  w += ((size_t)n * DH * 2 + 255) & ~255ull;
    _Float16* h1  = (_Float16*)w;  w += ((size_t)n * DH * 2 + 255) & ~255ull;
    _Float16* Wt1 = (_Float16*)w;  w += (size_t)DH * DH * 2;
    _Float16* Wt2 = (_Float16*)w;  w += (size_t)DH * DH * 2;
    float* deg    = (float*)w;  w += (size_t)n * 4;
    float* dinv   = (float*)w;  w += (size_t)n * 4;
    int*   row_ptr= (int*)w;    w += (size_t)(n + 1) * 4;
    int*   fill   = (int*)w;    w += (size_t)n * 4;
    int*   col    = (int*)w;    w += (size_t)(e + n + 64) * 4;   // +pad for clamp reads
    float* wgt    = (float*)w;  w += (size_t)(e + n + 64) * 4;   // +pad
    float* sbuf   = (float*)w;  w += (size_t)n * 4;
    int*   part   = (int*)w;    w += 4096;

    const int tb = 256;
    int nscan = (n + 1023) / 1024;
    int nb_init = (n + 255) / 256;
    k_init_tw<<<nb_init + 128, 256, 0, stream>>>(deg, fill, n, W1, Wt1, W2, Wt2);
    k_deg<<<(e + tb - 1) / tb, tb, 0, stream>>>(dst, deg, e);
    k_scan1<<<nscan, 1024, 0, stream>>>(deg, dinv, row_ptr, part, n);
    k_scan2<<<1, 64, 0, stream>>>(part, row_ptr, nscan, n);
    k_scan3<<<nscan, 1024, 0, stream>>>(row_ptr, part, dinv, col, wgt, fill, n);
    k_csr<<<(e + tb - 1) / tb, tb, 0, stream>>>(src, dst, dinv, row_ptr, fill, col, wgt, e);

    int ntiles = (n + 63) / 64;          // 64-row tiles, one per block
    k_gemm_lds<true><<<ntiles, 512, 0, stream>>>(x, Wt1, A, n);                 // A = x@W1 (cast fused)
    k_agg_h<<<(n + 3) / 4, 256, 0, stream>>>((const __half*)A, row_ptr, col, wgt, b1,
                                             (__half*)h1, n);                   // h1 (f16)
    k_gemm_lds<false><<<ntiles, 512, 0, stream>>>(h1, Wt2, A, n);               // A = h1@W2
    k_agg_f<<<(n + 3) / 4, 256, 0, stream>>>((const __half*)A, row_ptr, col, wgt, b2,
                                             We, out_h, sbuf, n);               // final h + s
    k_y<<<(e + tb - 1) / tb, tb, 0, stream>>>(src, dst, sbuf, be, out_y, e);
}